// Round 3
// baseline (924.467 us; speedup 1.0000x reference)
//
#include <hip/hip_runtime.h>
#include <hip/hip_bf16.h>
#include <stdint.h>

#define F 128
#define R 6
#define NTYPES 95
#define MTILE 64   // edges per block; 4 waves x 16 edges, B-frags computed in-register

typedef short bf16x8 __attribute__((ext_vector_type(8)));
typedef float floatx4 __attribute__((ext_vector_type(4)));

__device__ __forceinline__ unsigned short f2bf(float x) {
    union { float f; unsigned u; } cv; cv.f = x;
    unsigned u = cv.u;
    return (unsigned short)((u + 0x7FFFu + ((u >> 16) & 1u)) >> 16);  // RNE
}

// swish via v_rcp_f32 (~1 ulp) instead of IEEE div sequence (~10 instrs).
__device__ __forceinline__ float swishf(float x) {
    return x * __builtin_amdgcn_rcpf(1.0f + __expf(-x));
}

__device__ __forceinline__ floatx4 swish4(floatx4 v) {
    floatx4 r;
    #pragma unroll
    for (int i = 0; i < 4; ++i) r[i] = swishf(v[i]);
    return r;
}

// blocks 0..94:   embW[z][0:128]=emb[z]@W[0:128] + b (bias folded), embW[z][128:256]=emb[z]@W[128:256]
// blocks 95..158: w2t[n][k] = bf16(W[256+k][n])  (transposed K-contiguous for MFMA A-frags)
// blocks 159..162: wrtp[f][8] = {W_rbf[0..5][f], b_rbf[f], 0}  (per-feature packed, 4 KB)
__global__ void prep_kernel(const float* __restrict__ emb,
                            const float* __restrict__ W,
                            const float* __restrict__ bvec,
                            const float* __restrict__ W_rbf,
                            const float* __restrict__ b_rbf,
                            float* __restrict__ embW,
                            unsigned short* __restrict__ w2t,
                            float* __restrict__ wrtp) {
    int t = threadIdx.x;
    int b = blockIdx.x;
    if (b < NTYPES) {
        int c = t >> 7, f = t & 127;
        const float* er = emb + b * F;
        const float* Wc = W + c * F * F;
        float a = 0.f;
        #pragma unroll 8
        for (int k = 0; k < F; ++k) a = __builtin_fmaf(er[k], Wc[k * F + f], a);
        embW[b * 256 + c * F + f] = a + (c == 0 ? bvec[f] : 0.f);
    } else if (b < NTYPES + 64) {
        int idx = (b - NTYPES) * 256 + t;  // 0..16383
        int n = idx >> 7, k = idx & 127;
        w2t[n * F + k] = f2bf(W[(256 + k) * F + n]);
    } else {
        int idx = (b - NTYPES - 64) * 256 + t;  // 0..1023
        int f = idx >> 3, r = idx & 7;
        float v = (r < R) ? W_rbf[r * F + f] : (r == R ? b_rbf[f] : 0.f);
        wrtp[idx] = v;
    }
}

// Zero-LDS, zero-barrier edge kernel.
// Each lane (quad,l15) of wave w owns edge e = blk*64 + w*16 + l15 and computes
// its own MFMA B-fragment h[e][k = ks*32 + quad*8 + j] in registers.
__global__ __launch_bounds__(256, 4) void
edge_kernel(const int* __restrict__ Z,
            const float* __restrict__ rbf,
            const int* __restrict__ idnb_i,
            const int* __restrict__ idnb_j,
            const float* __restrict__ embW,
            const unsigned short* __restrict__ w2t,
            const float* __restrict__ wrtp,
            float* __restrict__ out,
            int E) {
    int t = threadIdx.x;
    int w = t >> 6;
    int lid = t & 63;
    int quad = lid >> 4;
    int l15 = lid & 15;

    long e = (long)blockIdx.x * MTILE + w * 16 + l15;
    bool ok = e < (long)E;
    long ec = ok ? e : (long)(E - 1);

    // early latency-hidden loads: Z gathers (L2) and this edge's 6 rbf values
    int zi = Z[idnb_i[ec]];
    int zj = Z[idnb_j[ec]];
    const float2* rp = (const float2*)(rbf + ec * R);
    float2 r01 = rp[0], r23 = rp[1], r45 = rp[2];

    floatx4 acc[8];
    #pragma unroll
    for (int ft = 0; ft < 8; ++ft) acc[ft] = (floatx4){0.f, 0.f, 0.f, 0.f};

    const bf16x8* w2v = (const bf16x8*)w2t;          // A-frags: [n][k] rows, 16 chunks each
    const floatx4* wp = (const floatx4*)wrtp;        // [f][2] float4: {w0..3},{w4,w5,bias,0}

    #pragma unroll
    for (int ks = 0; ks < 4; ++ks) {
        int fb = ks * 32 + quad * 8;                 // this lane's 8 k-features
        union { unsigned short s[8]; bf16x8 v; } bu;
        #pragma unroll
        for (int j = 0; j < 8; ++j) {
            int f = fb + j;
            floatx4 wa = wp[f * 2];
            floatx4 wb = wp[f * 2 + 1];
            float v = wb[2];                         // bias
            v = __builtin_fmaf(r01.x, wa[0], v);
            v = __builtin_fmaf(r01.y, wa[1], v);
            v = __builtin_fmaf(r23.x, wa[2], v);
            v = __builtin_fmaf(r23.y, wa[3], v);
            v = __builtin_fmaf(r45.x, wb[0], v);
            v = __builtin_fmaf(r45.y, wb[1], v);
            bu.s[j] = f2bf(swishf(v));
        }
        bf16x8 bfr = bu.v;
        #pragma unroll
        for (int ft = 0; ft < 8; ++ft) {
            // A-frag: A[m = ft*16+l15][k = ks*32 + quad*8 + j]  (32 KB L1-resident table)
            bf16x8 afr = w2v[(ft * 16 + l15) * 16 + ks * 4 + quad];
            acc[ft] = __builtin_amdgcn_mfma_f32_16x16x32_bf16(afr, bfr, acc[ft], 0, 0, 0);
        }
    }

    // ---- epilogue: + embW0[zi] + embW1[zj] (bias pre-folded), swish, dwordx4 store ----
    // D layout: col(l15) = edge, row(quad*4+reg) = feature -> lane holds 4 consecutive feats
    const floatx4* p0 = (const floatx4*)(embW + zi * 256);       // x1 @ W0 + b
    const floatx4* p1 = (const floatx4*)(embW + zj * 256 + F);   // x2 @ W1
    float* op = out + e * F;
    #pragma unroll
    for (int ft = 0; ft < 8; ++ft) {
        int f4 = ft * 4 + quad;                      // feature = ft*16 + quad*4 + 0..3
        floatx4 v = acc[ft] + p0[f4] + p1[f4];
        floatx4 r = swish4(v);
        if (ok) *(floatx4*)(op + f4 * 4) = r;
    }
}

extern "C" void kernel_launch(void* const* d_in, const int* in_sizes, int n_in,
                              void* d_out, int out_size, void* d_ws, size_t ws_size,
                              hipStream_t stream) {
    const int*   Z     = (const int*)d_in[0];
    const float* rbf   = (const float*)d_in[1];
    const int*   id_i  = (const int*)d_in[2];
    const int*   id_j  = (const int*)d_in[3];
    const float* emb   = (const float*)d_in[4];
    const float* W_rbf = (const float*)d_in[5];
    const float* b_rbf = (const float*)d_in[6];
    const float* W     = (const float*)d_in[7];
    const float* bvec  = (const float*)d_in[8];
    float* out = (float*)d_out;
    int E = in_sizes[2];

    float* embW = (float*)d_ws;                                   // 95*256*4 = 97280 B
    unsigned short* w2t = (unsigned short*)((char*)d_ws + 97280); // 128*128*2 = 32768 B
    float* wrtp = (float*)((char*)d_ws + 97280 + 32768);          // 128*8*4  = 4096 B

    prep_kernel<<<NTYPES + 64 + 4, 256, 0, stream>>>(emb, W, bvec, W_rbf, b_rbf,
                                                     embW, w2t, wrtp);
    int grid = (E + MTILE - 1) / MTILE;
    edge_kernel<<<grid, 256, 0, stream>>>(Z, rbf, id_i, id_j,
                                          embW, w2t, wrtp, out, E);
}

// Round 4
// 678.012 us; speedup vs baseline: 1.3635x; 1.3635x over previous
//
#include <hip/hip_runtime.h>
#include <hip/hip_bf16.h>
#include <stdint.h>

#define F 128
#define R 6
#define NTYPES 95
#define MTILE 64   // edges per block; 4 waves x 16 edges

typedef short bf16x8 __attribute__((ext_vector_type(8)));
typedef float floatx4 __attribute__((ext_vector_type(4)));

__device__ __forceinline__ unsigned short f2bf(float x) {
    union { float f; unsigned u; } cv; cv.f = x;
    unsigned u = cv.u;
    return (unsigned short)((u + 0x7FFFu + ((u >> 16) & 1u)) >> 16);  // RNE
}

// swish via v_rcp_f32 (~1 ulp) instead of IEEE div sequence.
__device__ __forceinline__ float swishf(float x) {
    return x * __builtin_amdgcn_rcpf(1.0f + __expf(-x));
}

__device__ __forceinline__ floatx4 swish4(floatx4 v) {
    floatx4 r;
    #pragma unroll
    for (int i = 0; i < 4; ++i) r[i] = swishf(v[i]);
    return r;
}

// blocks 0..94:   embW[z][0:128]=emb[z]@W[0:128]+b (bias folded), embW[z][128:256]=emb[z]@W[128:256]
// blocks 95..158: w2t[n][k] = bf16(W[256+k][n])  (transposed, K-contiguous chunks for MFMA A-frags)
// block  159:     wrtp2[r][f] (r-major, 8x128 f32): rows 0..5 = W_rbf, row 6 = b_rbf, row 7 = 0
__global__ void prep_kernel(const float* __restrict__ emb,
                            const float* __restrict__ W,
                            const float* __restrict__ bvec,
                            const float* __restrict__ W_rbf,
                            const float* __restrict__ b_rbf,
                            float* __restrict__ embW,
                            unsigned short* __restrict__ w2t,
                            float* __restrict__ wrtp2) {
    int t = threadIdx.x;
    int b = blockIdx.x;
    if (b < NTYPES) {
        int c = t >> 7, f = t & 127;
        const float* er = emb + b * F;
        const float* Wc = W + c * F * F;
        float a = 0.f;
        #pragma unroll 8
        for (int k = 0; k < F; ++k) a = __builtin_fmaf(er[k], Wc[k * F + f], a);
        embW[b * 256 + c * F + f] = a + (c == 0 ? bvec[f] : 0.f);
    } else if (b < NTYPES + 64) {
        int idx = (b - NTYPES) * 256 + t;  // 0..16383
        int n = idx >> 7, k = idx & 127;
        w2t[n * F + k] = f2bf(W[(256 + k) * F + n]);
    } else {
        for (int idx = t; idx < 8 * F; idx += 256) {
            int r = idx >> 7, f = idx & 127;
            wrtp2[idx] = (r < R) ? W_rbf[r * F + f] : (r == R ? b_rbf[f] : 0.f);
        }
    }
}

// LDS-table edge kernel: one barrier; hot tables (w2t 32KB swizzled, wrtp2 4KB) in LDS;
// per-lane in-register B-frags; embW gathers folded into the MFMA accumulator init.
__global__ __launch_bounds__(256, 4) void
edge_kernel(const int* __restrict__ Z,
            const float* __restrict__ rbf,
            const int* __restrict__ idnb_i,
            const int* __restrict__ idnb_j,
            const float* __restrict__ embW,
            const unsigned short* __restrict__ w2t,
            const float* __restrict__ wrtp2,
            float* __restrict__ out,
            int E) {
    // w2s: row n (out-feature) = 16 chunks of 8 bf16; chunk c stored at slot c ^ (n&15)
    // -> ds_read_b128 across 16 l15-lanes lands 2 lanes/4-bank-group = conflict-free.
    __shared__ __align__(16) short w2s[F * F];     // 32 KB
    __shared__ __align__(16) float wr_s[8 * F];    // 4 KB, r-major

    int t = threadIdx.x;
    int w = t >> 6;
    int lid = t & 63;
    int quad = lid >> 4;
    int l15 = lid & 15;

    long e = (long)blockIdx.x * MTILE + w * 16 + l15;
    bool ok = e < (long)E;
    long ec = ok ? e : (long)(E - 1);

    // start the gather chain as early as possible
    int ii = idnb_i[ec];
    int jj = idnb_j[ec];

    // ---- stage w2t -> LDS, swizzled; per instr: 64 lanes read 1KB contiguous ----
    const bf16x8* w2v = (const bf16x8*)w2t;
    #pragma unroll
    for (int j = 0; j < 8; ++j) {
        int chunk = j * 256 + t;           // 0..2047
        int n = chunk >> 4, c = chunk & 15;
        bf16x8 v = w2v[chunk];
        *(bf16x8*)(&w2s[n * F + ((c ^ (n & 15)) << 3)]) = v;
    }
    // ---- stage wrtp2 -> LDS (1024 floats = 256 float4, linear) ----
    ((floatx4*)wr_s)[t] = ((const floatx4*)wrtp2)[t];

    int zi = Z[ii], zj = Z[jj];
    const float2* rp = (const float2*)(rbf + ec * R);
    float2 r01 = rp[0], r23 = rp[1], r45 = rp[2];
    float rv[R] = {r01.x, r01.y, r23.x, r23.y, r45.x, r45.y};

    __syncthreads();

    // ---- acc init = embW0[zi] + embW1[zj]  (D[m=feat][n=edge]) ----
    // lane's features: f = ft*16 + quad*4 + 0..3  -> float4 index ft*4+quad
    const floatx4* p0 = (const floatx4*)(embW + zi * 256);       // x1@W0 + b
    const floatx4* p1 = (const floatx4*)(embW + zj * 256 + F);   // x2@W1
    floatx4 acc[8];
    #pragma unroll
    for (int ft = 0; ft < 8; ++ft) acc[ft] = p0[ft * 4 + quad] + p1[ft * 4 + quad];

    #pragma unroll
    for (int ks = 0; ks < 4; ++ks) {
        int fb = ks * 32 + quad * 8;       // this lane's 8 k-features
        // r-major weight reads: quad-distinct banks, l15-broadcast -> conflict-free
        floatx4 vA = *(const floatx4*)(&wr_s[6 * F + fb]);       // bias
        floatx4 vB = *(const floatx4*)(&wr_s[6 * F + fb + 4]);
        #pragma unroll
        for (int r = 0; r < R; ++r) {
            floatx4 wa = *(const floatx4*)(&wr_s[r * F + fb]);
            floatx4 wb = *(const floatx4*)(&wr_s[r * F + fb + 4]);
            #pragma unroll
            for (int s = 0; s < 4; ++s) {
                vA[s] = __builtin_fmaf(rv[r], wa[s], vA[s]);
                vB[s] = __builtin_fmaf(rv[r], wb[s], vB[s]);
            }
        }
        union { unsigned short s[8]; bf16x8 v; } bu;
        #pragma unroll
        for (int s = 0; s < 4; ++s) {
            bu.s[s]     = f2bf(swishf(vA[s]));
            bu.s[4 + s] = f2bf(swishf(vB[s]));
        }
        #pragma unroll
        for (int ft = 0; ft < 8; ++ft) {
            // A-frag: A[m=ft*16+l15][k=ks*32+quad*8+j], chunk (ks*4+quad) ^ l15 (swizzle)
            bf16x8 afr = *(const bf16x8*)(&w2s[(ft * 16 + l15) * F + (((ks * 4 + quad) ^ l15) << 3)]);
            acc[ft] = __builtin_amdgcn_mfma_f32_16x16x32_bf16(afr, bu.v, acc[ft], 0, 0, 0);
        }
    }

    // ---- epilogue: swish + dwordx4 store only (embW already in acc) ----
    float* op = out + e * F;
    #pragma unroll
    for (int ft = 0; ft < 8; ++ft) {
        floatx4 rres = swish4(acc[ft]);
        if (ok) *(floatx4*)(op + (ft * 4 + quad) * 4) = rres;
    }
}

extern "C" void kernel_launch(void* const* d_in, const int* in_sizes, int n_in,
                              void* d_out, int out_size, void* d_ws, size_t ws_size,
                              hipStream_t stream) {
    const int*   Z     = (const int*)d_in[0];
    const float* rbf   = (const float*)d_in[1];
    const int*   id_i  = (const int*)d_in[2];
    const int*   id_j  = (const int*)d_in[3];
    const float* emb   = (const float*)d_in[4];
    const float* W_rbf = (const float*)d_in[5];
    const float* b_rbf = (const float*)d_in[6];
    const float* W     = (const float*)d_in[7];
    const float* bvec  = (const float*)d_in[8];
    float* out = (float*)d_out;
    int E = in_sizes[2];

    float* embW = (float*)d_ws;                                   // 95*256*4 = 97280 B
    unsigned short* w2t = (unsigned short*)((char*)d_ws + 97280); // 128*128*2 = 32768 B
    float* wrtp2 = (float*)((char*)d_ws + 97280 + 32768);         // 8*128*4  = 4096 B

    prep_kernel<<<NTYPES + 64 + 1, 256, 0, stream>>>(emb, W, bvec, W_rbf, b_rbf,
                                                     embW, w2t, wrtp2);
    int grid = (E + MTILE - 1) / MTILE;
    edge_kernel<<<grid, 256, 0, stream>>>(Z, rbf, id_i, id_j,
                                          embW, w2t, wrtp2, out, E);
}